// Round 3
// baseline (160.524 us; speedup 1.0000x reference)
//
#include <hip/hip_runtime.h>

// Problem constants (reference: shape (2,1,160,192,160), win=9)
#define BB 2
#define DD 160
#define HH 192
#define WW 160
#define HW (HH * WW)
#define PAD 4
#define WIN 9
#define TH 16
#define TW 16
#define EXT 24            // TH+2*PAD == TW+2*PAD
#define XS_STR 25         // slice buffer row stride (24 cols + 1 pad)
#define SLOTS 600         // EXT * XS_STR
#define BUFSLOTS 1024     // padded so every wave issues the same #loads
#define WS_STR 20         // wsum row stride (2-way banks in P3 reads)
#define HS_STR 17         // hsum row stride (2-way banks in P4 reads)
#define CHUNK 20
#define NCHUNK 8          // DD / CHUNK
#define WT (WW / TW)      // 10
#define HT (HH / TH)      // 12
#define NBLK (WT * HT * NCHUNK * BB)  // 1920
#define EPS 1e-5f
#define INV_WS (1.0f / 729.0f)

// raw barrier that does NOT drain vmcnt (keeps async staging in flight)
__device__ __forceinline__ void bar_lgkm() {
  asm volatile("s_waitcnt lgkmcnt(0)" ::: "memory");
  __builtin_amdgcn_s_barrier();
  asm volatile("" ::: "memory");
}

// Issue one slice's staging: 4 global_load_lds per wave (x,y  x  k=0,1).
// LDS dest is wave-uniform base + lane*4 (linear); per-lane global address.
__device__ __forceinline__ void stage_slice(const float* __restrict__ gx,
                                            const float* __restrict__ gy,
                                            float* lx, float* ly,
                                            int of0, int of1, int wb) {
  __builtin_amdgcn_global_load_lds(
      (const __attribute__((address_space(1))) void*)(gx + of0),
      (__attribute__((address_space(3))) void*)(lx + wb), 4, 0, 0);
  __builtin_amdgcn_global_load_lds(
      (const __attribute__((address_space(1))) void*)(gy + of0),
      (__attribute__((address_space(3))) void*)(ly + wb), 4, 0, 0);
  __builtin_amdgcn_global_load_lds(
      (const __attribute__((address_space(1))) void*)(gx + of1),
      (__attribute__((address_space(3))) void*)(lx + 512 + wb), 4, 0, 0);
  __builtin_amdgcn_global_load_lds(
      (const __attribute__((address_space(1))) void*)(gy + of1),
      (__attribute__((address_space(3))) void*)(ly + 512 + wb), 4, 0, 0);
}

__global__ void __launch_bounds__(512) k_lncc(
    const float* __restrict__ x, const float* __restrict__ y,
    float* __restrict__ partials)
{
  __shared__ float xs[2][BUFSLOTS];
  __shared__ float ys[2][BUFSLOTS];
  __shared__ float wsum[5 * EXT * WS_STR];   // 2400 f
  __shared__ float hsum[5 * TH * HS_STR];    // 1360 f
  __shared__ float red[8];

  const int t = threadIdx.x;
  const int w0 = blockIdx.x * TW;
  const int h0 = blockIdx.y * TH;
  const int b = blockIdx.z >> 3;
  const int chunk = blockIdx.z & 7;
  const int dc0 = chunk * CHUNK;

  // ---- staging precompute: slot = k*512 + t; clamp OOB to offset 0 ----
  int of[2];
#pragma unroll
  for (int k = 0; k < 2; ++k) {
    int s = t + k * 512;
    int r = s / XS_STR, cl = s - r * XS_STR;
    int gh = h0 - PAD + r, gw = w0 - PAD + cl;
    bool ok = (s < SLOTS) & (cl < EXT) &
              ((unsigned)gh < (unsigned)HH) & ((unsigned)gw < (unsigned)WW);
    of[k] = ok ? (gh * WW + gw) : 0;
  }
  const int wb = t & ~63;  // wave-uniform slot base

  // ---- P2 task mapping (t < 480): c*96 + r*4 + q ----
  const int tq2 = t & 3;
  const int tr2 = (t >> 2) % 24;
  const int tc2 = t / 96;
  const bool aIsY = (tc2 == 1) | (tc2 == 3);
  const bool bIsY = (tc2 != 2);
  const bool useB = (tc2 >= 2);
  const bool row_ok = ((unsigned)(h0 - PAD + tr2) < (unsigned)HH);
  const int aroff = tr2 * XS_STR + tq2 * 4;
  const int ulo = (PAD - w0) > 0 ? (PAD - w0) : 0;                      // block-uniform
  const int uhi = (WW + PAD - w0) < EXT ? (WW + PAD - w0) : EXT;        // block-uniform

  // ---- P3 task mapping (t < 320): c*64 + w*4 + hq ----
  const int thq = t & 3;
  const int tw3 = (t >> 2) & 15;
  const int tc3 = t >> 6;

  // ---- P4 mapping: pair (even: c0,c1,c2 | odd: c3,c4) per output ----
  const int to = t >> 1, th4 = to >> 4, tw4 = to & 15;
  const bool odd = t & 1;

  // D-window shift registers (static idx -> VGPRs)
  float rA[WIN], rB[WIN], rC[WIN];
#pragma unroll
  for (int i = 0; i < WIN; ++i) { rA[i] = 0.f; rB[i] = 0.f; rC[i] = 0.f; }
  float runA = 0.f, runB = 0.f, runC = 0.f, acc = 0.f;

  const int g0 = dc0 - PAD;
  const int g1 = dc0 + CHUNK + PAD;
  const float* gx0 = x + (long)b * DD * HW;
  const float* gy0 = y + (long)b * DD * HW;

  // preload first slice (parity 0) if valid
  if (g0 >= 0)
    stage_slice(gx0 + (long)g0 * HW, gy0 + (long)g0 * HW,
                &xs[0][0], &ys[0][0], of[0], of[1], wb);

  for (int g = g0; g < g1; ++g) {
    const int p = (g - g0) & 1;
    const int gn = g + 1;
    const bool nv = (gn >= 0) && (gn < DD) && (gn < g1);
    if (nv)
      stage_slice(gx0 + (long)gn * HW, gy0 + (long)gn * HW,
                  &xs[p ^ 1][0], &ys[p ^ 1][0], of[0], of[1], wb);

    const bool gv = (g >= 0) && (g < DD);   // block-uniform
    float hA = 0.f, hB = 0.f, hC = 0.f;
    if (gv) {
      // wait for THIS slice's 4 loads (leave next slice's 4 in flight)
      if (nv) asm volatile("s_waitcnt vmcnt(4) lgkmcnt(0)" ::: "memory");
      else    asm volatile("s_waitcnt vmcnt(0) lgkmcnt(0)" ::: "memory");
      __builtin_amdgcn_s_barrier();
      asm volatile("" ::: "memory");

      const float* xsp = &xs[p][0];
      const float* ysp = &ys[p][0];

      // ---- P2: sliding W-filter, 480 quarter-row tasks ----
      if (t < 480) {
        const float* pa = aIsY ? ysp : xsp;
        const float* pb = bIsY ? ysp : xsp;
        float qv[12];
#pragma unroll
        for (int i = 0; i < 12; ++i) {
          int u = tq2 * 4 + i;
          float av = pa[aroff + i];
          float bv = pb[aroff + i];
          float v = useB ? av * bv : av;
          bool ok = row_ok & (u >= ulo) & (u < uhi);
          qv[i] = ok ? v : 0.f;
        }
        float s = 0.f;
#pragma unroll
        for (int i = 0; i < 9; ++i) s += qv[i];
        float* wr = &wsum[(tc2 * EXT + tr2) * WS_STR + tq2 * 4];
        wr[0] = s;
#pragma unroll
        for (int j = 1; j < 4; ++j) { s += qv[j + 8] - qv[j - 1]; wr[j] = s; }
      }
      bar_lgkm();

      // ---- P3: sliding H-filter, 320 quarter-col tasks ----
      if (t < 320) {
        const float* wc = &wsum[tc3 * EXT * WS_STR + tw3];
        float vv[12];
#pragma unroll
        for (int i = 0; i < 12; ++i) vv[i] = wc[(thq * 4 + i) * WS_STR];
        float s = 0.f;
#pragma unroll
        for (int i = 0; i < 9; ++i) s += vv[i];
        float* hc = &hsum[tc3 * TH * HS_STR + tw3];
        hc[(thq * 4) * HS_STR] = s;
#pragma unroll
        for (int j = 1; j < 4; ++j) {
          s += vv[j + 8] - vv[j - 1];
          hc[(thq * 4 + j) * HS_STR] = s;
        }
      }
      bar_lgkm();

      // ---- P4 reads: even lanes c0,c1,c2; odd lanes c3,c4 ----
      if (!odd) {
        hA = hsum[(0 * TH + th4) * HS_STR + tw4];
        hB = hsum[(1 * TH + th4) * HS_STR + tw4];
        hC = hsum[(2 * TH + th4) * HS_STR + tw4];
      } else {
        hA = hsum[(3 * TH + th4) * HS_STR + tw4];
        hB = hsum[(4 * TH + th4) * HS_STR + tw4];
      }
    }

    // ---- D-direction running sums (9-deep shift registers) ----
    runA += hA - rA[0];
    runB += hB - rB[0];
    runC += hC - rC[0];
#pragma unroll
    for (int i = 0; i < WIN - 1; ++i) { rA[i] = rA[i + 1]; rB[i] = rB[i + 1]; rC[i] = rC[i + 1]; }
    rA[WIN - 1] = hA; rB[WIN - 1] = hB; rC[WIN - 1] = hC;

    int d = g - PAD;
    if (d >= dc0) {                    // block-uniform
      float oA = __shfl_xor(runA, 1);  // even <- odd's syy
      float oB = __shfl_xor(runB, 1);  // even <- odd's sxy
      if (!odd) {
        float sx = runA, sy = runB, sxx = runC, syy = oA, sxy = oB;
        float cross = sxy - sx * sy * INV_WS;
        float xv = fmaxf(sxx - sx * sx * INV_WS, EPS);
        float yv = fmaxf(syy - sy * sy * INV_WS, EPS);
        acc += (cross * cross) / (xv * yv);
      }
    }
  }

  // ---- block reduction: wave shuffle + tiny LDS ----
#pragma unroll
  for (int off = 32; off > 0; off >>= 1) acc += __shfl_down(acc, off);
  if ((t & 63) == 0) red[t >> 6] = acc;
  __syncthreads();
  if (t == 0) {
    float s = 0.f;
#pragma unroll
    for (int i = 0; i < 8; ++i) s += red[i];
    int bid = (blockIdx.z * HT + blockIdx.y) * WT + blockIdx.x;
    partials[bid] = s;
  }
}

__global__ void __launch_bounds__(256) k_finalize(
    const float* __restrict__ partials, float* __restrict__ out)
{
  __shared__ double red[256];
  double s = 0.0;
  for (int i = threadIdx.x; i < NBLK; i += 256) s += (double)partials[i];
  red[threadIdx.x] = s;
  __syncthreads();
  for (int off = 128; off > 0; off >>= 1) {
    if (threadIdx.x < off) red[threadIdx.x] += red[threadIdx.x + off];
    __syncthreads();
  }
  if (threadIdx.x == 0) {
    const double Nvox = (double)BB * DD * HH * WW;
    out[0] = (float)(-red[0] / Nvox);
  }
}

extern "C" void kernel_launch(void* const* d_in, const int* in_sizes, int n_in,
                              void* d_out, int out_size, void* d_ws, size_t ws_size,
                              hipStream_t stream) {
  (void)in_sizes; (void)n_in; (void)out_size; (void)ws_size;
  const float* x = (const float*)d_in[0];
  const float* y = (const float*)d_in[1];
  float* out = (float*)d_out;
  float* partials = (float*)d_ws;

  dim3 grid(WT, HT, BB * NCHUNK);
  k_lncc<<<grid, 512, 0, stream>>>(x, y, partials);
  k_finalize<<<1, 256, 0, stream>>>(partials, out);
}

// Round 4
// 86.224 us; speedup vs baseline: 1.8617x; 1.8617x over previous
//
#include <hip/hip_runtime.h>

// Problem constants (reference: shape (2,1,160,192,160), win=9)
#define BB 2
#define DD 160
#define HH 192
#define WW 160
#define HW (HH * WW)
#define PAD 4
#define TH 16
#define TW 16
#define EXT 24              // TH+2*PAD == TW+2*PAD
#define XSTR 28             // xs row stride (words, 16B-aligned rows)
#define PLANE 768           // padded plane size (>= EXT*XSTR=672; write overflow pad)
#define SLOTS (EXT * XSTR)  // 672
#define WCS 456             // wsum channel stride (words; !=0 mod 32 for bank spread)
#define WJS 28              // wsum col(j) stride
#define HCS 272             // hsum channel stride
#define HHS 17              // hsum row(h) stride
#define CHUNK 28
#define NCH 6               // ceil(DD/CHUNK)
#define NITER 36            // CHUNK + 2*PAD, = 4*9 for static ring indexing
#define WT (WW / TW)        // 10
#define HT (HH / TH)        // 12
#define NBLK (WT * HT * NCH * BB)  // 1440
#define EPS 1e-5f
#define INV_WS (1.0f / 729.0f)

// barrier that waits LDS only — never drains vmcnt (keeps async loads in flight)
__device__ __forceinline__ void bar_lgkm() {
  asm volatile("s_waitcnt lgkmcnt(0)" ::: "memory");
  __builtin_amdgcn_s_barrier();
  asm volatile("" ::: "memory");
}

__global__ void __launch_bounds__(256) k_lncc(
    const float* __restrict__ x, const float* __restrict__ y,
    float* __restrict__ partials)
{
  // [parity][x/y][plane]
  __shared__ float sbuf[2][2][PLANE];     // 12.3 KB
  __shared__ float wsum[5 * WCS];         // 9.1 KB  layout [c][j][r], r-stride 1
  __shared__ float hsum[5 * HCS];         // 5.4 KB  layout [c][h][w], w-stride 1
  __shared__ float red[4];

  const int t = threadIdx.x;
  const int w0 = blockIdx.x * TW;
  const int h0 = blockIdx.y * TH;
  const int bz = blockIdx.z;
  const int b = bz / NCH;
  const int chunk = bz - b * NCH;
  const int dc0 = chunk * CHUNK;

  // ---- staging precompute (hoisted out of the slice loop) ----
  int off[3]; float msk[3];
#pragma unroll
  for (int k = 0; k < 3; ++k) {
    int s = t + 256 * k;
    int r = s / XSTR, cl = s - r * XSTR;
    int gh = h0 - PAD + r, gw = w0 - PAD + cl;
    bool ok = (s < SLOTS) & (cl < EXT) &
              ((unsigned)gh < (unsigned)HH) & ((unsigned)gw < (unsigned)WW);
    off[k] = ok ? (gh * WW + gw) : 0;
    msk[k] = ok ? 1.0f : 0.0f;
  }

  // ---- P2 constants (t<120): one full ext row per (channel,row) task ----
  const int c2 = t / 24, r2 = t - c2 * 24;
  const bool aIsY = (c2 == 1) | (c2 == 3);
  const bool bIsX = (c2 == 2);
  const bool useB = (c2 >= 2);
  const int paOff = (aIsY ? PLANE : 0) + r2 * XSTR;  // + p*2*PLANE
  const int pbOff = (bIsX ? 0 : PLANE) + r2 * XSTR;
  float* const wwr = &wsum[c2 * WCS + r2];           // + j*WJS

  // ---- P3 constants (t<80): one output col per (channel,col) task ----
  const int c3 = t / 16, w3 = t - c3 * 16;
  const float* const wrd = &wsum[c3 * WCS + w3 * WJS];  // + i (contiguous)
  float* const hwr = &hsum[c3 * HCS + w3];              // + h*HHS

  // ---- P4 constants: one output (h,w) per thread ----
  const int h4 = t >> 4, w4 = t & 15;
  const float* const hrd = &hsum[h4 * HHS + w4];        // + c*HCS

  const float* xb = x + (long)b * DD * HW;
  const float* yb = y + (long)b * DD * HW;

  // D-window ring, statically indexed via 9-unrolled loop -> pure VGPRs, no shifts
  float ring[9][5];
#pragma unroll
  for (int i = 0; i < 9; ++i)
#pragma unroll
    for (int c = 0; c < 5; ++c) ring[i][c] = 0.f;
  float run0 = 0.f, run1 = 0.f, run2 = 0.f, run3 = 0.f, run4 = 0.f, acc = 0.f;

  const int g0 = dc0 - PAD;

  // prologue: load slice g0 into regs (written to LDS at it=0)
  float vx0 = 0.f, vx1 = 0.f, vx2 = 0.f, vy0 = 0.f, vy1 = 0.f, vy2 = 0.f;
  if (g0 >= 0) {
    const float* xsl = xb + (long)g0 * HW;
    const float* ysl = yb + (long)g0 * HW;
    vx0 = xsl[off[0]]; vx1 = xsl[off[1]]; vx2 = xsl[off[2]];
    vy0 = ysl[off[0]]; vy1 = ysl[off[1]]; vy2 = ysl[off[2]];
  }

  for (int ito = 0; ito < NITER; ito += 9) {
#pragma unroll
    for (int jj = 0; jj < 9; ++jj) {
      const int it = ito + jj;
      const int g = g0 + it;
      const int p = it & 1;
      const bool gv = (g >= 0) && (g < DD);  // block-uniform
      float hv0 = 0.f, hv1 = 0.f, hv2 = 0.f, hv3 = 0.f, hv4 = 0.f;

      if (gv) {
        // write staged regs (slice g) -> sbuf[p]
        float* xd = &sbuf[p][0][0];
        float* yd = &sbuf[p][1][0];
        xd[t]       = vx0 * msk[0];
        yd[t]       = vy0 * msk[0];
        xd[t + 256] = vx1 * msk[1];
        yd[t + 256] = vy1 * msk[1];
        xd[t + 512] = vx2 * msk[2];
        yd[t + 512] = vy2 * msk[2];
      }
      // issue next slice's loads; they stay in flight across all 3 phases
      {
        const int gn = g + 1;
        if ((gn >= 0) && (gn < DD) && (it + 1 < NITER)) {
          const float* xsl = xb + (long)gn * HW;
          const float* ysl = yb + (long)gn * HW;
          vx0 = xsl[off[0]]; vx1 = xsl[off[1]]; vx2 = xsl[off[2]];
          vy0 = ysl[off[0]]; vy1 = ysl[off[1]]; vy2 = ysl[off[2]];
        }
      }

      if (gv) {
        bar_lgkm();  // A: sbuf[p] visible
        // ---- P2: sliding W-filter, full ext row per task ----
        if (t < 120) {
          const int pbase = p * (2 * PLANE);
          const float* pa = &sbuf[0][0][0] + pbase + paOff;
          const float* pb = &sbuf[0][0][0] + pbase + pbOff;
          float q[EXT];
#pragma unroll
          for (int i = 0; i < EXT; ++i) {
            float a = pa[i];
            float bv = pb[i];
            q[i] = useB ? a * bv : a;
          }
          float s = ((q[0] + q[1]) + (q[2] + q[3])) +
                    ((q[4] + q[5]) + (q[6] + q[7])) + q[8];
          wwr[0] = s;
#pragma unroll
          for (int j = 1; j < TW; ++j) {
            s += q[j + 8] - q[j - 1];
            wwr[j * WJS] = s;
          }
        }
        bar_lgkm();  // B
        // ---- P3: sliding H-filter, contiguous reads (transposed wsum) ----
        if (t < 80) {
          float v[EXT];
#pragma unroll
          for (int i = 0; i < EXT; ++i) v[i] = wrd[i];
          float s = ((v[0] + v[1]) + (v[2] + v[3])) +
                    ((v[4] + v[5]) + (v[6] + v[7])) + v[8];
          hwr[0] = s;
#pragma unroll
          for (int h = 1; h < TH; ++h) {
            s += v[h + 8] - v[h - 1];
            hwr[h * HHS] = s;
          }
        }
        bar_lgkm();  // C
        hv0 = hrd[0];
        hv1 = hrd[HCS];
        hv2 = hrd[2 * HCS];
        hv3 = hrd[3 * HCS];
        hv4 = hrd[4 * HCS];
      }

      // ---- D running sums; ring[jj] static -> no register shifting ----
      run0 += hv0 - ring[jj][0]; ring[jj][0] = hv0;
      run1 += hv1 - ring[jj][1]; ring[jj][1] = hv1;
      run2 += hv2 - ring[jj][2]; ring[jj][2] = hv2;
      run3 += hv3 - ring[jj][3]; ring[jj][3] = hv3;
      run4 += hv4 - ring[jj][4]; ring[jj][4] = hv4;

      if (it >= 8) {
        const int d = g - PAD;          // = dc0 + it - 8
        if (d < DD) {                   // block-uniform; tail chunk guard
          float cross = fmaf(-run0 * INV_WS, run1, run4);
          float xv = fmaxf(fmaf(-run0 * INV_WS, run0, run2), EPS);
          float yv = fmaxf(fmaf(-run1 * INV_WS, run1, run3), EPS);
          acc += (cross * cross) * __builtin_amdgcn_rcpf(xv * yv);
        }
      }
    }
  }

  // ---- block reduction ----
#pragma unroll
  for (int o = 32; o > 0; o >>= 1) acc += __shfl_down(acc, o);
  if ((t & 63) == 0) red[t >> 6] = acc;
  __syncthreads();
  if (t == 0) {
    int bid = (bz * HT + blockIdx.y) * WT + blockIdx.x;
    partials[bid] = (red[0] + red[1]) + (red[2] + red[3]);
  }
}

__global__ void __launch_bounds__(256) k_finalize(
    const float* __restrict__ partials, float* __restrict__ out)
{
  __shared__ double red[256];
  double s = 0.0;
  for (int i = threadIdx.x; i < NBLK; i += 256) s += (double)partials[i];
  red[threadIdx.x] = s;
  __syncthreads();
  for (int o = 128; o > 0; o >>= 1) {
    if (threadIdx.x < o) red[threadIdx.x] += red[threadIdx.x + o];
    __syncthreads();
  }
  if (threadIdx.x == 0) {
    const double Nvox = (double)BB * DD * HH * WW;
    out[0] = (float)(-red[0] / Nvox);
  }
}

extern "C" void kernel_launch(void* const* d_in, const int* in_sizes, int n_in,
                              void* d_out, int out_size, void* d_ws, size_t ws_size,
                              hipStream_t stream) {
  (void)in_sizes; (void)n_in; (void)out_size; (void)ws_size;
  const float* x = (const float*)d_in[0];
  const float* y = (const float*)d_in[1];
  float* out = (float*)d_out;
  float* partials = (float*)d_ws;

  dim3 grid(WT, HT, BB * NCH);
  k_lncc<<<grid, 256, 0, stream>>>(x, y, partials);
  k_finalize<<<1, 256, 0, stream>>>(partials, out);
}